// Round 10
// baseline (105.148 us; speedup 1.0000x reference)
//
#include <hip/hip_runtime.h>

// ---- problem constants ----
#define HOP 160
#define NROWS 402
#define NTAPS 400
#define T_SIG 9600000
#define N_FRAMES 60001
#define PAD 200

typedef __bf16 bf16x8 __attribute__((ext_vector_type(8)));
typedef float f32x16 __attribute__((ext_vector_type(16)));
typedef unsigned short u16x8 __attribute__((ext_vector_type(8)));
typedef unsigned short u16x4 __attribute__((ext_vector_type(4)));
typedef unsigned int u32x4 __attribute__((ext_vector_type(4)));

__device__ __forceinline__ unsigned short f2bf(float f) {
    unsigned int u = __builtin_bit_cast(unsigned int, f);
    u += 0x7fffu + ((u >> 16) & 1u);
    return (unsigned short)(u >> 16);
}

__device__ __forceinline__ void gll16(const void* g, void* l) {
    __builtin_amdgcn_global_load_lds(
        (const __attribute__((address_space(1))) unsigned int*)g,
        (__attribute__((address_space(3))) unsigned int*)l, 16, 0, 0);
}

// ================= TIER 1: A-stationary GEMM =================
// C[row][t] = sum_k basis[row][k] * sig[t*160 + k - 200]
// ws: Apack only (425984 B): [bm=0..3][ka=0..25][g=0..1][row=0..127] 16B frags
//   frag = bf16 basis[bm*128+row][ka*16+g*8 .. +8), zero-padded.
// Block: FULL 128-row A-tile resident in LDS (106.5 KB, frag-major ->
// gll16 linear dest + contiguous a-reads), one 128-frame sig window
// (43.5 KB, fp32->bf16 converted in-kernel: no prep_sig pass). 150 KB LDS,
// 1 block/CU, 4 waves of 64x64. K-loop touches NO global memory:
// 26 phases x {4 ds_read_b128 + 4 MFMA}. Each block processes 4 windows.

#define KA 26
#define A_LDS_B 106496        // 26*2*128*16
#define SIG_LDS_B 43552       // 21776 bf16 elems (padded +8 per 160)
#define NW 4
#define NCH 118               // ceil(469 / NW)
#define NEED1 425984UL

// prep: basis fp32 -> Apack frag-major (26624 slots of 16B)
__global__ void prep_a(const float* __restrict__ basis,
                       unsigned short* __restrict__ ap) {
    int s = blockIdx.x * 256 + threadIdx.x;   // 104*256 = 26624 exactly
    int bm = s / 6656, rem = s % 6656;
    int ka = rem >> 8;
    int g = (rem >> 7) & 1;
    int row = rem & 127;
    int m = bm * 128 + row;
    int k0 = ka * 16 + g * 8;
    u16x8 v;
#pragma unroll
    for (int j = 0; j < 8; ++j) {
        int k = k0 + j;
        float f = (m < NROWS && k < NTAPS) ? basis[m * NTAPS + k] : 0.0f;
        v[j] = f2bf(f);
    }
    *reinterpret_cast<u16x8*>(ap + (size_t)s * 8) = v;
}

#define STORE_ACC(A, R0, T) do { if ((T) < (long)N_FRAMES) { _Pragma("unroll") \
    for (int r = 0; r < 16; ++r) { \
        int row = (R0) + (r & 3) + 8 * (r >> 2); \
        if (row < NROWS) out[(long)row * N_FRAMES + (T)] = (A)[r]; \
    } } } while (0)

__launch_bounds__(256, 1)
__global__ void stft_gemm(const float* __restrict__ sig,
                          const unsigned short* __restrict__ apack,
                          float* __restrict__ out) {
    __shared__ __align__(16) char lds[A_LDS_B + SIG_LDS_B];  // 150048 B
    char* aL = lds;
    char* sL = lds + A_LDS_B;
    const int tid = threadIdx.x;
    const int bm = blockIdx.x & 3;
    const int ch = blockIdx.x >> 2;

    // stage the whole A-tile once (async DMA; drained by first barrier)
    {
        const char* ab = (const char*)apack + (size_t)bm * A_LDS_B;
#pragma unroll
        for (int it = 0; it < KA; ++it) {
            int slot = it * 256 + tid;      // 6656 slots exactly
            gll16(ab + slot * 16, aL + slot * 16);
        }
    }

    const int lane = tid & 63;
    const int w = tid >> 6;
    const int wm = w >> 1;                  // 64-row half
    const int wf = w & 1;                   // 64-frame half
    const int l31 = lane & 31;
    const int g = lane >> 5;

    // a: slot ((ka*2+g)*128 + row); lanes 0-31 contiguous 512B -> 0 conflicts
    const char* aBase0 = aL + g * 2048 + (wm * 64 + l31) * 16;
    // b: frame stride 336 B (measured conflict-free in R7/R9)
    const char* bBase = sL + (wf * 64 + l31) * 336 + g * 16;
    const int rBase = bm * 128 + wm * 64 + 4 * g;

#pragma unroll 1
    for (int win = 0; win < NW; ++win) {
        const int bt = ch * NW + win;
        if (bt >= 469) break;

        // stage sig window: fp32 global -> bf16 padded LDS (guarded)
        const long sbase = (long)bt * (128 * HOP) - PAD;
        for (int idx = tid; idx < 5184; idx += 256) {
            const int e = idx * 4;
            const long g0 = sbase + e;
            float4 v;
            if (g0 >= 0 && g0 + 4 <= (long)T_SIG) {
                v = *reinterpret_cast<const float4*>(sig + g0);
            } else {
                v.x = (g0 + 0 >= 0 && g0 + 0 < (long)T_SIG) ? sig[g0 + 0] : 0.0f;
                v.y = (g0 + 1 >= 0 && g0 + 1 < (long)T_SIG) ? sig[g0 + 1] : 0.0f;
                v.z = (g0 + 2 >= 0 && g0 + 2 < (long)T_SIG) ? sig[g0 + 2] : 0.0f;
                v.w = (g0 + 3 >= 0 && g0 + 3 < (long)T_SIG) ? sig[g0 + 3] : 0.0f;
            }
            u16x4 s4;
            s4[0] = f2bf(v.x); s4[1] = f2bf(v.y); s4[2] = f2bf(v.z); s4[3] = f2bf(v.w);
            const int pos = e + 8 * (e / 160);   // 4-chunk stays in one 160-block
            *reinterpret_cast<u16x4*>(sL + pos * 2) = s4;
        }
        __syncthreads();   // sig visible (and A-DMA drained on first window)

        f32x16 acc00 = {0,0,0,0,0,0,0,0,0,0,0,0,0,0,0,0};
        f32x16 acc01 = {0,0,0,0,0,0,0,0,0,0,0,0,0,0,0,0};
        f32x16 acc10 = {0,0,0,0,0,0,0,0,0,0,0,0,0,0,0,0};
        f32x16 acc11 = {0,0,0,0,0,0,0,0,0,0,0,0,0,0,0,0};

        // pure LDS->MFMA K-loop: no global ops, no barriers
#pragma unroll
        for (int ka = 0; ka < KA; ++ka) {
            const int sc = ka * 32 + (ka >= 10 ? 16 : 0) + (ka >= 20 ? 16 : 0);
            bf16x8 a0 = *reinterpret_cast<const bf16x8*>(aBase0 + ka * 4096);
            bf16x8 a1 = *reinterpret_cast<const bf16x8*>(aBase0 + ka * 4096 + 512);
            bf16x8 b0 = *reinterpret_cast<const bf16x8*>(bBase + sc);
            bf16x8 b1 = *reinterpret_cast<const bf16x8*>(bBase + 10752 + sc);
            acc00 = __builtin_amdgcn_mfma_f32_32x32x16_bf16(a0, b0, acc00, 0, 0, 0);
            acc01 = __builtin_amdgcn_mfma_f32_32x32x16_bf16(a0, b1, acc01, 0, 0, 0);
            acc10 = __builtin_amdgcn_mfma_f32_32x32x16_bf16(a1, b0, acc10, 0, 0, 0);
            acc11 = __builtin_amdgcn_mfma_f32_32x32x16_bf16(a1, b1, acc11, 0, 0, 0);
        }

        const long tBase = (long)bt * 128 + wf * 64 + l31;
        STORE_ACC(acc00, rBase, tBase);
        STORE_ACC(acc01, rBase, tBase + 32);
        STORE_ACC(acc10, rBase + 32, tBase);
        STORE_ACC(acc11, rBase + 32, tBase + 32);
        __syncthreads();   // all reads done before next window's overwrite
    }
}

// ================= TIER 2: R3 fallback (proven 65-73 us) =================
#define MT 13
#define KS 26
#define FPB 128
#define MSPLIT 3
#define NBT ((N_FRAMES + FPB - 1) / FPB)
#define SPAN (127*HOP + 416)
#define SPAN4 (SPAN/4)
#define LDSE 21776

__global__ void stft_prep2(const float* __restrict__ basis,
                           unsigned short* __restrict__ packed) {
    int tid = blockIdx.x * 256 + threadIdx.x;
    if (tid >= MT * KS * 64) return;
    int lane = tid & 63;
    int frag = tid >> 6;
    int ks = frag % KS;
    int mt = frag / KS;
    int row = mt * 32 + (lane & 31);
    int colb = ks * 16 + (lane >> 5) * 8;
    u16x8 v;
#pragma unroll
    for (int i = 0; i < 8; ++i) {
        int col = colb + i;
        float f = (row < NROWS && col < NTAPS) ? basis[row * NTAPS + col] : 0.0f;
        v[i] = f2bf(f);
    }
    *reinterpret_cast<u16x8*>(packed + (size_t)tid * 8) = v;
}

__launch_bounds__(256, 3)
__global__ void stft_mfma2(const float* __restrict__ sig,
                           const unsigned short* __restrict__ packedA,
                           float* __restrict__ out) {
    __shared__ unsigned short sl[LDSE];
    const int tid = threadIdx.x;
    const int bt = blockIdx.x % NBT;
    const int bmm = blockIdx.x / NBT;
    const long sbase = (long)bt * (FPB * HOP) - PAD;
    for (int idx = tid; idx < SPAN4; idx += 256) {
        const int e = idx * 4;
        const long g0 = sbase + e;
        float4 v;
        if (g0 >= 0 && g0 + 4 <= (long)T_SIG) {
            v = *reinterpret_cast<const float4*>(sig + g0);
        } else {
            v.x = (g0 + 0 >= 0 && g0 + 0 < (long)T_SIG) ? sig[g0 + 0] : 0.0f;
            v.y = (g0 + 1 >= 0 && g0 + 1 < (long)T_SIG) ? sig[g0 + 1] : 0.0f;
            v.z = (g0 + 2 >= 0 && g0 + 2 < (long)T_SIG) ? sig[g0 + 2] : 0.0f;
            v.w = (g0 + 3 >= 0 && g0 + 3 < (long)T_SIG) ? sig[g0 + 3] : 0.0f;
        }
        u16x4 s;
        s[0] = f2bf(v.x); s[1] = f2bf(v.y); s[2] = f2bf(v.z); s[3] = f2bf(v.w);
        const int pos = e + 8 * (e / 160);
        *reinterpret_cast<u16x4*>(&sl[pos]) = s;
    }
    __syncthreads();
    const int lane = tid & 63;
    const int w = tid >> 6;
    const int l31 = lane & 31;
    const int g = lane >> 5;
    const int lf = w * 32 + l31;
    const long t = (long)bt * FPB + lf;
    const int mt0 = (bmm == 0) ? 0 : 5 + 4 * (bmm - 1);
    const int mtN = (bmm == 0) ? 5 : 4;
    const unsigned short* bbase = &sl[lf * 168 + g * 8];
    const int rowg = 4 * g;
#pragma unroll 1
    for (int mi = 0; mi < mtN; ++mi) {
        const int mt = mt0 + mi;
        f32x16 acc = {0,0,0,0,0,0,0,0,0,0,0,0,0,0,0,0};
        const unsigned short* pA = packedA + ((size_t)(mt * KS) * 64 + lane) * 8;
#pragma unroll
        for (int ks = 0; ks < KS; ++ks) {
            const bf16x8 a = *reinterpret_cast<const bf16x8*>(pA + (size_t)ks * 512);
            const bf16x8 b = *reinterpret_cast<const bf16x8*>(bbase + ks * 16 + 8 * (ks / 10));
            acc = __builtin_amdgcn_mfma_f32_32x32x16_bf16(a, b, acc, 0, 0, 0);
        }
        if (t < N_FRAMES) {
            const int rb = mt * 32 + rowg;
#pragma unroll
            for (int r = 0; r < 16; ++r) {
                const int row = rb + (r & 3) + 8 * (r >> 2);
                if (row < NROWS) out[(long)row * N_FRAMES + t] = acc[r];
            }
        }
        __syncthreads();
    }
}

// ================= TIER 3: naive =================
__global__ void stft_naive(const float* __restrict__ sig,
                           const float* __restrict__ basis,
                           float* __restrict__ out) {
    long idx = (long)blockIdx.x * 256 + threadIdx.x;
    if (idx >= (long)NROWS * N_FRAMES) return;
    int row = (int)(idx / N_FRAMES);
    int tt = (int)(idx % N_FRAMES);
    long s0 = (long)tt * HOP - PAD;
    float acc = 0.0f;
    for (int n = 0; n < NTAPS; ++n) {
        long s = s0 + n;
        float x = (s >= 0 && s < (long)T_SIG) ? sig[s] : 0.0f;
        acc = fmaf(x, basis[row * NTAPS + n], acc);
    }
    out[idx] = acc;
}

extern "C" void kernel_launch(void* const* d_in, const int* in_sizes, int n_in,
                              void* d_out, int out_size, void* d_ws, size_t ws_size,
                              hipStream_t stream) {
    (void)in_sizes; (void)n_in; (void)out_size;
    const float* sig = (const float*)d_in[0];
    const float* basis = (const float*)d_in[1];
    float* out = (float*)d_out;
    if (ws_size >= NEED1) {
        unsigned short* ap = (unsigned short*)d_ws;
        prep_a<<<104, 256, 0, stream>>>(basis, ap);
        stft_gemm<<<4 * NCH, 256, 0, stream>>>(sig, ap, out);
    } else if (ws_size >= (size_t)MT * KS * 64 * 8 * sizeof(unsigned short)) {
        unsigned short* packed = (unsigned short*)d_ws;
        stft_prep2<<<(MT * KS * 64 + 255) / 256, 256, 0, stream>>>(basis, packed);
        stft_mfma2<<<NBT * MSPLIT, 256, 0, stream>>>(sig, packed, out);
    } else {
        long total = (long)NROWS * N_FRAMES;
        stft_naive<<<(int)((total + 255) / 256), 256, 0, stream>>>(sig, basis, out);
    }
}

// Round 11
// 78.165 us; speedup vs baseline: 1.3452x; 1.3452x over previous
//
#include <hip/hip_runtime.h>

// ---- problem constants ----
#define HOP 160
#define NROWS 402
#define NTAPS 400
#define T_SIG 9600000
#define N_FRAMES 60001
#define PAD 200

// ---- tiling ----
#define MT 13                 // 13 m-tiles of 32 rows (416 padded)
#define KS 26                 // 26 k-steps of 16 taps (416 padded)
#define FPB 128               // frames per block
#define NBT 469               // frame blocks
#define SPAN4 5184            // (127*160+416)/4 float4 chunks per window
#define LDSE 21776            // bf16 elems: 20736 + 8 per 160 (R7-proven layout)
#define NEED1 346112UL        // Apack bytes: 13*26*64*16

typedef __bf16 bf16x8 __attribute__((ext_vector_type(8)));
typedef float f32x16 __attribute__((ext_vector_type(16)));
typedef unsigned short u16x8 __attribute__((ext_vector_type(8)));
typedef unsigned short u16x4 __attribute__((ext_vector_type(4)));
typedef unsigned int u32x4 __attribute__((ext_vector_type(4)));

__device__ __forceinline__ unsigned short f2bf(float f) {
    // round-to-nearest-even fp32 -> bf16 (inputs finite)
    unsigned int u = __builtin_bit_cast(unsigned int, f);
    u += 0x7fffu + ((u >> 16) & 1u);
    return (unsigned short)(u >> 16);
}

// prep: basis fp32 -> bf16 frag-order (R1-proven layout):
// packed[((mt*KS+ks)*64 + lane)*8 + i] = bf16(basis[mt*32+(lane&31)][ks*16+(lane>>5)*8+i])
__global__ void prep_a(const float* __restrict__ basis,
                       unsigned short* __restrict__ packed) {
    int tid = blockIdx.x * 256 + threadIdx.x;
    if (tid >= MT * KS * 64) return;
    int lane = tid & 63;
    int frag = tid >> 6;
    int ks = frag % KS;
    int mt = frag / KS;
    int row = mt * 32 + (lane & 31);
    int colb = ks * 16 + (lane >> 5) * 8;
    u16x8 v;
#pragma unroll
    for (int i = 0; i < 8; ++i) {
        int col = colb + i;
        float f = (row < NROWS && col < NTAPS) ? basis[row * NTAPS + col] : 0.0f;
        v[i] = f2bf(f);
    }
    *reinterpret_cast<u16x8*>(packed + (size_t)tid * 8) = v;
}

#define STORE_ACC(A, R0, T) do { if ((T) < (long)N_FRAMES) { _Pragma("unroll") \
    for (int r = 0; r < 16; ++r) { \
        int row = (R0) + (r & 3) + 8 * (r >> 2); \
        if (row < NROWS) out[(long)row * N_FRAMES + (T)] = (A)[r]; \
    } } } while (0)

// C[row][t] = sum_k basis[row][k] * sig[t*160 + k - 200]
// A-in-REGISTERS via inline-asm global_load_dwordx4 (asm defs cannot be
// rematerialized/sunk -- defeats the R4/R5/R6 codegen failure). Each wave
// owns one 32-row m-tile x 128 frames: 26 A-frags = 104 pinned VGPRs,
// 4 accs = 64 VGPRs. K-loop: 26 x {4 ds_read_b128 (B) + 4 MFMA}; no
// global ops, no barriers, no A-traffic. LDS = sig window only (43.5 KB,
// R7-proven padded layout) -> 2 blocks/CU at ~210 VGPR (2 waves/SIMD).
__launch_bounds__(256, 2)
__global__ void stft_areg(const float* __restrict__ sig,
                          const unsigned short* __restrict__ apack,
                          float* __restrict__ out) {
    __shared__ unsigned short sl[LDSE];
    const int tid = threadIdx.x;
    const int bm = blockIdx.x & 3;          // bm fastest: neighbors share sig (L2)
    const int bt = blockIdx.x >> 2;
    const int lane = tid & 63;
    const int w = tid >> 6;
    const int mt = bm * 4 + w;              // wave's m-tile; real if < 13

    // (1) issue the wave's 26 A-frag loads via asm: pinned VGPR destinations.
    u32x4 a4[KS];
    if (mt < MT) {
        const char* ab = (const char*)apack + ((size_t)(mt * KS) * 64 + lane) * 16;
#pragma unroll
        for (int ks = 0; ks < KS; ++ks) {
            asm volatile("global_load_dwordx4 %0, %1, off"
                         : "=v"(a4[ks])
                         : "v"(ab + (size_t)ks * 1024));
        }
    }

    // (2) stage sig window fp32 -> bf16 LDS (coalesced float4, edge-guarded)
    const long sbase = (long)bt * (FPB * HOP) - PAD;
    for (int idx = tid; idx < SPAN4; idx += 256) {
        const int e = idx * 4;
        const long g0 = sbase + e;
        float4 v;
        if (g0 >= 0 && g0 + 4 <= (long)T_SIG) {
            v = *reinterpret_cast<const float4*>(sig + g0);
        } else {
            v.x = (g0 + 0 >= 0 && g0 + 0 < (long)T_SIG) ? sig[g0 + 0] : 0.0f;
            v.y = (g0 + 1 >= 0 && g0 + 1 < (long)T_SIG) ? sig[g0 + 1] : 0.0f;
            v.z = (g0 + 2 >= 0 && g0 + 2 < (long)T_SIG) ? sig[g0 + 2] : 0.0f;
            v.w = (g0 + 3 >= 0 && g0 + 3 < (long)T_SIG) ? sig[g0 + 3] : 0.0f;
        }
        u16x4 s4;
        s4[0] = f2bf(v.x); s4[1] = f2bf(v.y); s4[2] = f2bf(v.z); s4[3] = f2bf(v.w);
        const int pos = e + 8 * (e / 160);  // 4-chunk never crosses a 160 block
        *reinterpret_cast<u16x4*>(&sl[pos]) = s4;
    }
    __syncthreads();
    // asm loads are OPAQUE to the compiler's waitcnt model: drain explicitly
    // and fence the scheduler so no MFMA is hoisted above the wait (rule #18).
    asm volatile("s_waitcnt vmcnt(0)" ::: "memory");
    __builtin_amdgcn_sched_barrier(0);

    if (mt >= MT) return;                   // idle wave slots (13..15)

    const int l31 = lane & 31;
    const int g = lane >> 5;
    // B-frag base: frame stride 336 B, +g*16; col j adds j*32 frames = j*10752 B
    const char* bBase = (const char*)sl + l31 * 336 + g * 16;

    f32x16 acc0 = {0,0,0,0,0,0,0,0,0,0,0,0,0,0,0,0};
    f32x16 acc1 = {0,0,0,0,0,0,0,0,0,0,0,0,0,0,0,0};
    f32x16 acc2 = {0,0,0,0,0,0,0,0,0,0,0,0,0,0,0,0};
    f32x16 acc3 = {0,0,0,0,0,0,0,0,0,0,0,0,0,0,0,0};

    // (3) pure LDS->MFMA K-loop; A comes from pinned registers.
#pragma unroll
    for (int ka = 0; ka < KS; ++ka) {
        const int sc = ka * 32 + (ka >= 10 ? 16 : 0) + (ka >= 20 ? 16 : 0);
        const bf16x8 a = __builtin_bit_cast(bf16x8, a4[ka]);
        bf16x8 b0 = *reinterpret_cast<const bf16x8*>(bBase + sc);
        bf16x8 b1 = *reinterpret_cast<const bf16x8*>(bBase + 10752 + sc);
        bf16x8 b2 = *reinterpret_cast<const bf16x8*>(bBase + 21504 + sc);
        bf16x8 b3 = *reinterpret_cast<const bf16x8*>(bBase + 32256 + sc);
        acc0 = __builtin_amdgcn_mfma_f32_32x32x16_bf16(a, b0, acc0, 0, 0, 0);
        acc1 = __builtin_amdgcn_mfma_f32_32x32x16_bf16(a, b1, acc1, 0, 0, 0);
        acc2 = __builtin_amdgcn_mfma_f32_32x32x16_bf16(a, b2, acc2, 0, 0, 0);
        acc3 = __builtin_amdgcn_mfma_f32_32x32x16_bf16(a, b3, acc3, 0, 0, 0);
    }

    // (4) stores: C/D map row=(r&3)+8*(r>>2)+4*g, col=lane&31 (HW-verified)
    const int rb = mt * 32 + 4 * g;
    const long tb = (long)bt * FPB + l31;
    STORE_ACC(acc0, rb, tb);
    STORE_ACC(acc1, rb, tb + 32);
    STORE_ACC(acc2, rb, tb + 64);
    STORE_ACC(acc3, rb, tb + 96);
}

// ---- fallback: correct-but-slow naive ----
__global__ void stft_naive(const float* __restrict__ sig,
                           const float* __restrict__ basis,
                           float* __restrict__ out) {
    long idx = (long)blockIdx.x * 256 + threadIdx.x;
    if (idx >= (long)NROWS * N_FRAMES) return;
    int row = (int)(idx / N_FRAMES);
    int tt = (int)(idx % N_FRAMES);
    long s0 = (long)tt * HOP - PAD;
    float acc = 0.0f;
    for (int n = 0; n < NTAPS; ++n) {
        long s = s0 + n;
        float x = (s >= 0 && s < (long)T_SIG) ? sig[s] : 0.0f;
        acc = fmaf(x, basis[row * NTAPS + n], acc);
    }
    out[idx] = acc;
}

extern "C" void kernel_launch(void* const* d_in, const int* in_sizes, int n_in,
                              void* d_out, int out_size, void* d_ws, size_t ws_size,
                              hipStream_t stream) {
    (void)in_sizes; (void)n_in; (void)out_size;
    const float* sig = (const float*)d_in[0];
    const float* basis = (const float*)d_in[1];
    float* out = (float*)d_out;
    if (ws_size >= NEED1) {
        unsigned short* ap = (unsigned short*)d_ws;
        prep_a<<<(MT * KS * 64 + 255) / 256, 256, 0, stream>>>(basis, ap);
        stft_areg<<<NBT * 4, 256, 0, stream>>>(sig, ap, out);
    } else {
        long total = (long)NROWS * N_FRAMES;
        stft_naive<<<(int)((total + 255) / 256), 256, 0, stream>>>(sig, basis, out);
    }
}